// Round 1
// baseline (1098.382 us; speedup 1.0000x reference)
//
#include <hip/hip_runtime.h>

#define NN 100000
#define NE 1600000
#define NG 1024
#define DIN 128
#define D1 100
#define D2 20
#define DSELF 16
#define BN_EPS 1e-5f

// ---------------- transpose small weights ----------------
__global__ void k_prep(const float* __restrict__ W1, const float* __restrict__ W2,
                       const float* __restrict__ W2p,
                       float* __restrict__ W1T, float* __restrict__ W2T,
                       float* __restrict__ W2pT) {
    int id = blockIdx.x * 256 + threadIdx.x;
    if (id < DIN * D1) {                       // g1_W1 [128][100] -> [100][128]
        int k = id / D1, j = id % D1;
        W1T[j * DIN + k] = W1[id];
    } else if (id < DIN * D1 + D1 * D1) {      // g1_W2 [100][100] -> [100][100]T
        int id2 = id - DIN * D1;
        int k = id2 / D1, j = id2 % D1;
        W2T[j * D1 + k] = W2[id2];
    } else if (id < DIN * D1 + D1 * D1 + D2 * D2) {  // g2_W2 [20][20] -> T
        int id3 = id - (DIN * D1 + D1 * D1);
        int k = id3 / D2, j = id3 % D2;
        W2pT[j * D2 + k] = W2p[id3];
    }
}

// ---------------- z1 = feat @ W1 (row per lane, W uniform -> scalar loads) ----
__global__ __launch_bounds__(256) void k_gemm1(const float* __restrict__ feat,
                                               const float* __restrict__ W1T,
                                               float* __restrict__ z1) {
    int row = blockIdx.x * 256 + threadIdx.x;
    if (row >= NN) return;
    float4 a[32];
    const float4* fp = (const float4*)(feat + (size_t)row * DIN);
#pragma unroll
    for (int i = 0; i < 32; i++) a[i] = fp[i];
    float* zrow = z1 + (size_t)row * D1;
    for (int j = 0; j < D1; j += 4) {
        float a0 = 0.f, a1 = 0.f, a2 = 0.f, a3 = 0.f;
        const float4* w0 = (const float4*)(W1T + (j + 0) * DIN);
        const float4* w1 = (const float4*)(W1T + (j + 1) * DIN);
        const float4* w2 = (const float4*)(W1T + (j + 2) * DIN);
        const float4* w3 = (const float4*)(W1T + (j + 3) * DIN);
#pragma unroll
        for (int kk = 0; kk < 32; kk++) {
            float4 av = a[kk];
            float4 b0 = w0[kk], b1 = w1[kk], b2 = w2[kk], b3 = w3[kk];
            a0 += av.x * b0.x + av.y * b0.y + av.z * b0.z + av.w * b0.w;
            a1 += av.x * b1.x + av.y * b1.y + av.z * b1.z + av.w * b1.w;
            a2 += av.x * b2.x + av.y * b2.y + av.z * b2.z + av.w * b2.w;
            a3 += av.x * b3.x + av.y * b3.y + av.z * b3.z + av.w * b3.w;
        }
        float4 o; o.x = a0; o.y = a1; o.z = a2; o.w = a3;
        *(float4*)(zrow + j) = o;
    }
}

// ---------------- CSR build ----------------
__global__ void k_deg(const int* __restrict__ dst, int* __restrict__ deg) {
    int e = blockIdx.x * 256 + threadIdx.x;
    if (e < NE) atomicAdd(&deg[dst[e]], 1);
}

__global__ void k_scan1(const int* __restrict__ deg, int* __restrict__ offs,
                        int* __restrict__ bsum) {
    __shared__ int s[1024];
    int t = threadIdx.x;
    int i = blockIdx.x * 1024 + t;
    int v = (i < NN) ? deg[i] : 0;
    s[t] = v;
    __syncthreads();
    for (int off = 1; off < 1024; off <<= 1) {
        int x = (t >= off) ? s[t - off] : 0;
        __syncthreads();
        s[t] += x;
        __syncthreads();
    }
    if (i < NN) offs[i] = s[t] - v;          // exclusive within chunk
    if (t == 1023) bsum[blockIdx.x] = s[t];  // chunk total
}

__global__ void k_scan2(int* __restrict__ bsum) {  // 98 chunks, single block
    __shared__ int s[128];
    int t = threadIdx.x;
    int v = (t < 98) ? bsum[t] : 0;
    s[t] = v;
    __syncthreads();
    for (int off = 1; off < 128; off <<= 1) {
        int x = (t >= off) ? s[t - off] : 0;
        __syncthreads();
        s[t] += x;
        __syncthreads();
    }
    if (t < 98) bsum[t] = s[t] - v;  // exclusive chunk offsets
}

__global__ void k_scan3(int* __restrict__ offs, const int* __restrict__ bsum) {
    int i = blockIdx.x * 256 + threadIdx.x;
    if (i < NN) offs[i] += bsum[i >> 10];
}

__global__ void k_fill(const int* __restrict__ src, const int* __restrict__ dst,
                       const int* __restrict__ offs, int* __restrict__ fill,
                       int* __restrict__ srcS) {
    int e = blockIdx.x * 256 + threadIdx.x;
    if (e >= NE) return;
    int d = dst[e];
    int slot = offs[d] + atomicAdd(&fill[d], 1);
    srcS[slot] = src[e];
}

// ---------------- u1 = z1 + gather-sum (wave per node, 100 cols) -------------
__global__ __launch_bounds__(256) void k_agg1(const float* __restrict__ z1,
                                              const int* __restrict__ offs,
                                              const int* __restrict__ deg,
                                              const int* __restrict__ srcS,
                                              float* __restrict__ u1) {
    int w = threadIdx.x >> 6, l = threadIdx.x & 63;
    int n = blockIdx.x * 4 + w;
    if (n >= NN) return;
    int d = deg[n], base = offs[n];
    float a0 = 0.f, a1 = 0.f;
    for (int i = 0; i < d; i++) {
        const float* zr = z1 + (size_t)srcS[base + i] * D1;
        a0 += zr[l];
        if (l < D1 - 64) a1 += zr[l + 64];
    }
    const float* zn = z1 + (size_t)n * D1;
    float* un = u1 + (size_t)n * D1;
    un[l] = zn[l] + a0;
    if (l < D1 - 64) un[l + 64] = zn[l + 64] + a1;
}

// ---------------- BN stats (train mode, biased var) ----------------
template <int D>
__global__ void k_bnstat(const float* __restrict__ u, float* __restrict__ bsumv,
                         float* __restrict__ bsq) {
    int c = threadIdx.x;
    if (c >= D) return;
    int r0 = blockIdx.x * 256;
    int r1 = r0 + 256; if (r1 > NN) r1 = NN;
    float s = 0.f, q = 0.f;
    for (int r = r0; r < r1; r++) {
        float v = u[(size_t)r * D + c];
        s += v; q += v * v;
    }
    atomicAdd(&bsumv[c], s);
    atomicAdd(&bsq[c], q);
}

template <int D>
__global__ void k_bnfin(const float* __restrict__ bsumv, const float* __restrict__ bsq,
                        const float* __restrict__ gamma, const float* __restrict__ beta,
                        float* __restrict__ sc, float* __restrict__ sh) {
    int c = threadIdx.x;
    if (c >= D) return;
    float mean = bsumv[c] * (1.f / NN);
    float var = bsq[c] * (1.f / NN) - mean * mean;
    float inv = rsqrtf(var + BN_EPS);
    float s = gamma[c] * inv;
    sc[c] = s;
    sh[c] = beta[c] - mean * s;
}

// ------ fused: relu(bn1(u1)) @ g1_W2 + b2 -> relu -> @ g2_W1 = z2 ------------
__global__ __launch_bounds__(256) void k_m2(const float* __restrict__ u1,
                                            const float* __restrict__ sc,
                                            const float* __restrict__ sh,
                                            const float* __restrict__ W2T,
                                            const float* __restrict__ b2,
                                            const float* __restrict__ W1p,
                                            float* __restrict__ z2) {
    int row = blockIdx.x * 256 + threadIdx.x;
    if (row >= NN) return;
    float4 x[25];
    const float4* up = (const float4*)(u1 + (size_t)row * D1);
#pragma unroll
    for (int i = 0; i < 25; i++) {
        float4 v = up[i];
        float4 S = *(const float4*)(sc + 4 * i);
        float4 H = *(const float4*)(sh + 4 * i);
        v.x = fmaxf(v.x * S.x + H.x, 0.f);
        v.y = fmaxf(v.y * S.y + H.y, 0.f);
        v.z = fmaxf(v.z * S.z + H.z, 0.f);
        v.w = fmaxf(v.w * S.w + H.w, 0.f);
        x[i] = v;
    }
    float acc[D2];
#pragma unroll
    for (int c = 0; c < D2; c++) acc[c] = 0.f;
    for (int j = 0; j < D1; j++) {
        float h = b2[j];
        const float4* w = (const float4*)(W2T + j * D1);
#pragma unroll
        for (int kk = 0; kk < 25; kk++) {
            float4 a = x[kk], b = w[kk];
            h += a.x * b.x + a.y * b.y + a.z * b.z + a.w * b.w;
        }
        h = fmaxf(h, 0.f);
        const float* wp = W1p + j * D2;
#pragma unroll
        for (int c = 0; c < D2; c++) acc[c] += h * wp[c];
    }
    float* zr = z2 + (size_t)row * D2;
#pragma unroll
    for (int c = 0; c < D2; c += 4) {
        float4 o; o.x = acc[c]; o.y = acc[c + 1]; o.z = acc[c + 2]; o.w = acc[c + 3];
        *(float4*)(zr + c) = o;
    }
}

// ---------------- u2 = z2 + gather-sum (12 nodes x 20 cols per block) --------
__global__ __launch_bounds__(256) void k_agg2(const float* __restrict__ z2,
                                              const int* __restrict__ offs,
                                              const int* __restrict__ deg,
                                              const int* __restrict__ srcS,
                                              float* __restrict__ u2) {
    int t = threadIdx.x;
    if (t >= 240) return;
    int n = blockIdx.x * 12 + t / 20;
    int c = t % 20;
    if (n >= NN) return;
    int d = deg[n], base = offs[n];
    float a = 0.f;
    for (int i = 0; i < d; i++) a += z2[(size_t)srcS[base + i] * D2 + c];
    u2[(size_t)n * D2 + c] = z2[(size_t)n * D2 + c] + a;
}

// ------ fused: relu(bn2(u2)) @ g2_W2 + b2 -> relu = h2 ------------
__global__ __launch_bounds__(256) void k_m3(const float* __restrict__ u2,
                                            const float* __restrict__ sc,
                                            const float* __restrict__ sh,
                                            const float* __restrict__ W2pT,
                                            const float* __restrict__ b2p,
                                            float* __restrict__ h2) {
    int row = blockIdx.x * 256 + threadIdx.x;
    if (row >= NN) return;
    float4 y[5];
    const float4* up = (const float4*)(u2 + (size_t)row * D2);
#pragma unroll
    for (int i = 0; i < 5; i++) {
        float4 v = up[i];
        float4 S = *(const float4*)(sc + 4 * i);
        float4 H = *(const float4*)(sh + 4 * i);
        v.x = fmaxf(v.x * S.x + H.x, 0.f);
        v.y = fmaxf(v.y * S.y + H.y, 0.f);
        v.z = fmaxf(v.z * S.z + H.z, 0.f);
        v.w = fmaxf(v.w * S.w + H.w, 0.f);
        y[i] = v;
    }
    float hrow[D2];
#pragma unroll
    for (int j = 0; j < D2; j++) {
        float h = b2p[j];
        const float4* w = (const float4*)(W2pT + j * D2);
#pragma unroll
        for (int kk = 0; kk < 5; kk++) {
            float4 a = y[kk], b = w[kk];
            h += a.x * b.x + a.y * b.y + a.z * b.z + a.w * b.w;
        }
        hrow[j] = fmaxf(h, 0.f);
    }
    float* hr = h2 + (size_t)row * D2;
#pragma unroll
    for (int c = 0; c < D2; c += 4) {
        float4 o; o.x = hrow[c]; o.y = hrow[c + 1]; o.z = hrow[c + 2]; o.w = hrow[c + 3];
        *(float4*)(hr + c) = o;
    }
}

// ---------------- per-graph ranges (node2graph is sorted) ----------------
__global__ void k_starts(const int* __restrict__ n2g, int* __restrict__ starts) {
    int i = blockIdx.x * 256 + threadIdx.x;
    if (i >= NN) return;
    int g = n2g[i];
    if (i == 0) {
        for (int x = 0; x <= g; x++) starts[x] = 0;
    } else {
        int gp = n2g[i - 1];
        for (int x = gp + 1; x <= g; x++) starts[x] = i;
    }
    if (i == NN - 1) {
        for (int x = g + 1; x <= NG; x++) starts[x] = NN;
    }
}

__global__ void k_pool(const float* __restrict__ h2, const int* __restrict__ starts,
                       float* __restrict__ hg) {
    int g = blockIdx.x;
    int j = threadIdx.x;
    if (j >= D2) return;
    int s0 = starts[g], s1 = starts[g + 1];
    float a = 0.f;
    for (int n = s0; n < s1; n++) a += h2[(size_t)n * D2 + j];
    float cnt = (float)(s1 - s0);
    if (cnt < 1.f) cnt = 1.f;
    hg[g * D2 + j] = a / cnt;
}

// ---------------- a1 = kron(hg, self_feat) @ fc1_W ----------------
__global__ void k_head1(const float* __restrict__ hg, const float* __restrict__ sf,
                        const float* __restrict__ fc1W, float* __restrict__ a1) {
    int b = blockIdx.x * 8 + threadIdx.x / 32;
    int c = threadIdx.x % 32;
    if (b >= NG) return;
    const float* hgb = hg + b * D2;
    const float* sfb = sf + b * DSELF;
    float acc = 0.f;
    for (int i = 0; i < D2; i++) {
        float hi = hgb[i];
#pragma unroll
        for (int j = 0; j < DSELF; j++)
            acc += hi * sfb[j] * fc1W[(i * DSELF + j) * 32 + c];
    }
    a1[b * 32 + c] = acc;
}

// ---------------- single-block head: bn1->relu->fc2->bn2->relu->fc3 ----------
__global__ __launch_bounds__(1024) void k_head2(
    const float* __restrict__ a1, const float* __restrict__ g1,
    const float* __restrict__ be1, const float* __restrict__ fc2W,
    const float* __restrict__ g2, const float* __restrict__ be2,
    const float* __restrict__ fc3W, const float* __restrict__ fc3b,
    float* __restrict__ out) {
    int t = threadIdx.x;
    int lane = t & 63, w = t >> 6;
    __shared__ float s1[16][32], s2[16][32];
    __shared__ float sc[32], sh[32], sc2[8], sh2[8];
    float x[32];
    const float4* ap = (const float4*)(a1 + t * 32);
#pragma unroll
    for (int i = 0; i < 8; i++) {
        float4 v = ap[i];
        x[4 * i] = v.x; x[4 * i + 1] = v.y; x[4 * i + 2] = v.z; x[4 * i + 3] = v.w;
    }
#pragma unroll
    for (int c = 0; c < 32; c++) {
        float v = x[c], q = v * v;
        for (int o = 32; o > 0; o >>= 1) {
            v += __shfl_down(v, o, 64);
            q += __shfl_down(q, o, 64);
        }
        if (lane == 0) { s1[w][c] = v; s2[w][c] = q; }
    }
    __syncthreads();
    if (t < 32) {
        float s = 0.f, q = 0.f;
        for (int ww = 0; ww < 16; ww++) { s += s1[ww][t]; q += s2[ww][t]; }
        float mean = s * (1.f / NG);
        float var = q * (1.f / NG) - mean * mean;
        float inv = rsqrtf(var + BN_EPS);
        float scl = g1[t] * inv;
        sc[t] = scl;
        sh[t] = be1[t] - mean * scl;
    }
    __syncthreads();
#pragma unroll
    for (int c = 0; c < 32; c++) x[c] = fmaxf(x[c] * sc[c] + sh[c], 0.f);
    float y[8];
#pragma unroll
    for (int p = 0; p < 8; p++) {
        float a = 0.f;
#pragma unroll
        for (int c = 0; c < 32; c++) a += x[c] * fc2W[c * 8 + p];
        y[p] = a;
    }
    __syncthreads();  // done reading s1/s2 for bn1
#pragma unroll
    for (int p = 0; p < 8; p++) {
        float v = y[p], q = v * v;
        for (int o = 32; o > 0; o >>= 1) {
            v += __shfl_down(v, o, 64);
            q += __shfl_down(q, o, 64);
        }
        if (lane == 0) { s1[w][p] = v; s2[w][p] = q; }
    }
    __syncthreads();
    if (t < 8) {
        float s = 0.f, q = 0.f;
        for (int ww = 0; ww < 16; ww++) { s += s1[ww][t]; q += s2[ww][t]; }
        float mean = s * (1.f / NG);
        float var = q * (1.f / NG) - mean * mean;
        float inv = rsqrtf(var + BN_EPS);
        float scl = g2[t] * inv;
        sc2[t] = scl;
        sh2[t] = be2[t] - mean * scl;
    }
    __syncthreads();
    float o = fc3b[0];
#pragma unroll
    for (int p = 0; p < 8; p++) {
        float yy = fmaxf(y[p] * sc2[p] + sh2[p], 0.f);
        o += yy * fc3W[p];
    }
    out[t] = o;
}

extern "C" void kernel_launch(void* const* d_in, const int* in_sizes, int n_in,
                              void* d_out, int out_size, void* d_ws, size_t ws_size,
                              hipStream_t stream) {
    // inputs (setup_inputs dict order)
    const float* feat    = (const float*)d_in[0];
    const float* sf      = (const float*)d_in[1];
    const int*   esrc    = (const int*)d_in[2];
    const int*   edst    = (const int*)d_in[3];
    const int*   n2g     = (const int*)d_in[4];
    const float* g1W1    = (const float*)d_in[5];
    // d_in[6] g1_b1: cancels in BN1
    const float* g1gam   = (const float*)d_in[7];
    const float* g1bet   = (const float*)d_in[8];
    const float* g1W2    = (const float*)d_in[9];
    const float* g1b2    = (const float*)d_in[10];
    const float* g2W1    = (const float*)d_in[11];
    // d_in[12] g2_b1: cancels in BN2
    const float* g2gam   = (const float*)d_in[13];
    const float* g2bet   = (const float*)d_in[14];
    const float* g2W2    = (const float*)d_in[15];
    const float* g2b2    = (const float*)d_in[16];
    const float* fc1W    = (const float*)d_in[17];
    // d_in[18] fc1_b: cancels in head BN1
    const float* hbn1g   = (const float*)d_in[19];
    const float* hbn1b   = (const float*)d_in[20];
    const float* fc2W    = (const float*)d_in[21];
    // d_in[22] fc2_b: cancels in head BN2
    const float* hbn2g   = (const float*)d_in[23];
    const float* hbn2b   = (const float*)d_in[24];
    const float* fc3W    = (const float*)d_in[25];
    const float* fc3b    = (const float*)d_in[26];
    float* out = (float*)d_out;

    // ---- workspace bump allocator (16B aligned) ----
    char* w = (char*)d_ws;
    size_t off = 0;
    auto alloc = [&](size_t bytes) -> char* {
        char* p = w + off;
        off += (bytes + 15) & ~(size_t)15;
        return p;
    };
    float* z1   = (float*)alloc((size_t)NN * D1 * 4);  // 40 MB (reused for z2/u2/h2)
    float* u1   = (float*)alloc((size_t)NN * D1 * 4);  // 40 MB
    // zeroed region (one memset): deg, fill, bn stats
    char* zero_base = w + off;
    int*   deg   = (int*)alloc(NN * 4);
    int*   fill  = (int*)alloc(NN * 4);
    float* bn1s  = (float*)alloc(D1 * 4);
    float* bn1q  = (float*)alloc(D1 * 4);
    float* bn2s  = (float*)alloc(D2 * 4);
    float* bn2q  = (float*)alloc(D2 * 4);
    size_t zero_sz = (size_t)((w + off) - zero_base);
    int*   offs  = (int*)alloc(NN * 4);
    int*   bsum  = (int*)alloc(128 * 4);
    int*   srcS  = (int*)alloc((size_t)NE * 4);
    int*   starts= (int*)alloc((NG + 1) * 4);
    float* W1T   = (float*)alloc(DIN * D1 * 4);
    float* W2T   = (float*)alloc(D1 * D1 * 4);
    float* W2pT  = (float*)alloc(D2 * D2 * 4);
    float* sc1   = (float*)alloc(D1 * 4);
    float* sh1   = (float*)alloc(D1 * 4);
    float* sc2   = (float*)alloc(D2 * 4);
    float* sh2   = (float*)alloc(D2 * 4);
    float* hg    = (float*)alloc(NG * D2 * 4);
    float* a1    = (float*)alloc(NG * 32 * 4);
    // z2/u2/h2 alias the z1 region (z1 dead after k_agg1)
    float* z2 = z1;
    float* u2 = z1 + 2000000;
    float* h2 = z1 + 4000000;
    (void)in_sizes; (void)n_in; (void)out_size; (void)ws_size;

    hipMemsetAsync(zero_base, 0, zero_sz, stream);

    k_prep<<<91, 256, 0, stream>>>(g1W1, g1W2, g2W2, W1T, W2T, W2pT);
    k_gemm1<<<(NN + 255) / 256, 256, 0, stream>>>(feat, W1T, z1);

    k_deg<<<(NE + 255) / 256, 256, 0, stream>>>(edst, deg);
    k_scan1<<<98, 1024, 0, stream>>>(deg, offs, bsum);
    k_scan2<<<1, 128, 0, stream>>>(bsum);
    k_scan3<<<(NN + 255) / 256, 256, 0, stream>>>(offs, bsum);
    k_fill<<<(NE + 255) / 256, 256, 0, stream>>>(esrc, edst, offs, fill, srcS);

    k_agg1<<<(NN + 3) / 4, 256, 0, stream>>>(z1, offs, deg, srcS, u1);
    k_bnstat<D1><<<(NN + 255) / 256, 128, 0, stream>>>(u1, bn1s, bn1q);
    k_bnfin<D1><<<1, 128, 0, stream>>>(bn1s, bn1q, g1gam, g1bet, sc1, sh1);
    k_m2<<<(NN + 255) / 256, 256, 0, stream>>>(u1, sc1, sh1, W2T, g1b2, g2W1, z2);

    k_agg2<<<(NN + 11) / 12, 256, 0, stream>>>(z2, offs, deg, srcS, u2);
    k_bnstat<D2><<<(NN + 255) / 256, 128, 0, stream>>>(u2, bn2s, bn2q);
    k_bnfin<D2><<<1, 128, 0, stream>>>(bn2s, bn2q, g2gam, g2bet, sc2, sh2);
    k_m3<<<(NN + 255) / 256, 256, 0, stream>>>(u2, sc2, sh2, W2pT, g2b2, h2);

    k_starts<<<(NN + 255) / 256, 256, 0, stream>>>(n2g, starts);
    k_pool<<<NG, 64, 0, stream>>>(h2, starts, hg);
    k_head1<<<NG / 8, 256, 0, stream>>>(hg, sf, fc1W, a1);
    k_head2<<<1, 1024, 0, stream>>>(a1, hbn1g, hbn1b, fc2W, hbn2g, hbn2b, fc3W, fc3b, out);
}

// Round 2
// 776.183 us; speedup vs baseline: 1.4151x; 1.4151x over previous
//
#include <hip/hip_runtime.h>

#define NN 100000
#define NE 1600000
#define NG 1024
#define DIN 128
#define D1 100
#define D2 20
#define DSELF 16
#define BN_EPS 1e-5f

// ---------------- transpose g2_W2 only (used by k_m3) ----------------
__global__ void k_prep(const float* __restrict__ W2p, float* __restrict__ W2pT) {
    int id = blockIdx.x * 256 + threadIdx.x;
    if (id < D2 * D2) {
        int k = id / D2, j = id % D2;
        W2pT[j * D2 + k] = W2p[id];
    }
}

// ---------------- z1 = feat @ W1 : 64-row tile, LDS k-major, s_load weights --
__global__ __launch_bounds__(256) void k_gemm1(const float* __restrict__ feat,
                                               const float* __restrict__ W1,
                                               float* __restrict__ z1) {
    __shared__ float As[128 * 65];  // k-major, pad 65 -> 2-way (free)
    int t = threadIdx.x;
    int row0 = blockIdx.x * 64;
    // stage 64 rows x 128 cols, coalesced float4 reads
#pragma unroll
    for (int i = 0; i < 8; i++) {
        int p = i * 256 + t;   // float4 index
        int r = p >> 5, cq = p & 31;
        int row = row0 + r; if (row >= NN) row = NN - 1;
        float4 v = *(const float4*)(feat + (size_t)row * DIN + cq * 4);
        As[(4 * cq + 0) * 65 + r] = v.x;
        As[(4 * cq + 1) * 65 + r] = v.y;
        As[(4 * cq + 2) * 65 + r] = v.z;
        As[(4 * cq + 3) * 65 + r] = v.w;
    }
    __syncthreads();
    int cg = __builtin_amdgcn_readfirstlane(t >> 6);  // wave-uniform col group
    int r = t & 63;
    int j0 = cg * 25;
    float acc[25];
#pragma unroll
    for (int m = 0; m < 25; m++) acc[m] = 0.f;
    for (int k = 0; k < DIN; k++) {
        float a = As[k * 65 + r];
        const float* wr = W1 + k * D1 + j0;  // wave-uniform -> s_load
#pragma unroll
        for (int m = 0; m < 25; m++) acc[m] = fmaf(a, wr[m], acc[m]);
    }
    // epilogue: LDS round-trip for coalesced global stores
    __syncthreads();
#pragma unroll
    for (int m = 0; m < 25; m++) As[r * 100 + j0 + m] = acc[m];
    __syncthreads();
#pragma unroll
    for (int i = 0; i < 25; i++) {
        int p = i * 256 + t;
        int rr = p / 100, c = p % 100;
        int row = row0 + rr;
        if (row < NN) z1[(size_t)row * D1 + c] = As[rr * 100 + c];
    }
}

// ---------------- CSR build ----------------
__global__ void k_deg(const int* __restrict__ dst, int* __restrict__ deg) {
    int e = blockIdx.x * 256 + threadIdx.x;
    if (e < NE) atomicAdd(&deg[dst[e]], 1);
}

__global__ void k_scan1(const int* __restrict__ deg, int* __restrict__ offs,
                        int* __restrict__ bsum) {
    __shared__ int s[1024];
    int t = threadIdx.x;
    int i = blockIdx.x * 1024 + t;
    int v = (i < NN) ? deg[i] : 0;
    s[t] = v;
    __syncthreads();
    for (int off = 1; off < 1024; off <<= 1) {
        int x = (t >= off) ? s[t - off] : 0;
        __syncthreads();
        s[t] += x;
        __syncthreads();
    }
    if (i < NN) offs[i] = s[t] - v;
    if (t == 1023) bsum[blockIdx.x] = s[t];
}

__global__ void k_scan2(int* __restrict__ bsum) {
    __shared__ int s[128];
    int t = threadIdx.x;
    int v = (t < 98) ? bsum[t] : 0;
    s[t] = v;
    __syncthreads();
    for (int off = 1; off < 128; off <<= 1) {
        int x = (t >= off) ? s[t - off] : 0;
        __syncthreads();
        s[t] += x;
        __syncthreads();
    }
    if (t < 98) bsum[t] = s[t] - v;
}

__global__ void k_scan3(int* __restrict__ offs, const int* __restrict__ bsum) {
    int i = blockIdx.x * 256 + threadIdx.x;
    if (i < NN) offs[i] += bsum[i >> 10];
}

__global__ void k_fill(const int* __restrict__ src, const int* __restrict__ dst,
                       const int* __restrict__ offs, int* __restrict__ fill,
                       int* __restrict__ srcS) {
    int e = blockIdx.x * 256 + threadIdx.x;
    if (e >= NE) return;
    int d = dst[e];
    int slot = offs[d] + atomicAdd(&fill[d], 1);
    srcS[slot] = src[e];
}

// ---------------- u1 = z1 + gather-sum (wave per node, scalar idx loads) -----
__global__ __launch_bounds__(256) void k_agg1(const float* __restrict__ z1,
                                              const int* __restrict__ offs,
                                              const int* __restrict__ deg,
                                              const int* __restrict__ srcS,
                                              float* __restrict__ u1) {
    int wq = __builtin_amdgcn_readfirstlane(threadIdx.x >> 6);
    int l = threadIdx.x & 63;
    int n = blockIdx.x * 4 + wq;
    if (n >= NN) return;
    int d = deg[n], base = offs[n];
    float a0 = 0.f, a1 = 0.f, b0 = 0.f, b1 = 0.f;
    int i = 0;
    for (; i + 2 <= d; i += 2) {
        const float* p0 = z1 + (size_t)srcS[base + i] * D1;
        const float* p1 = z1 + (size_t)srcS[base + i + 1] * D1;
        float x0 = p0[l], x1 = p1[l];
        float y0 = (l < 36) ? p0[l + 64] : 0.f;
        float y1 = (l < 36) ? p1[l + 64] : 0.f;
        a0 += x0; b0 += x1; a1 += y0; b1 += y1;
    }
    if (i < d) {
        const float* p0 = z1 + (size_t)srcS[base + i] * D1;
        a0 += p0[l];
        if (l < 36) a1 += p0[l + 64];
    }
    const float* zn = z1 + (size_t)n * D1;
    float* un = u1 + (size_t)n * D1;
    un[l] = zn[l] + a0 + b0;
    if (l < 36) un[l + 64] = zn[l + 64] + a1 + b1;
}

// ---------------- BN stats (train mode, biased var) ----------------
template <int D>
__global__ void k_bnstat(const float* __restrict__ u, float* __restrict__ bsumv,
                         float* __restrict__ bsq) {
    int c = threadIdx.x;
    if (c >= D) return;
    int r0 = blockIdx.x * 256;
    int r1 = r0 + 256; if (r1 > NN) r1 = NN;
    float s = 0.f, q = 0.f;
    for (int r = r0; r < r1; r++) {
        float v = u[(size_t)r * D + c];
        s += v; q += v * v;
    }
    atomicAdd(&bsumv[c], s);
    atomicAdd(&bsq[c], q);
}

template <int D>
__global__ void k_bnfin(const float* __restrict__ bsumv, const float* __restrict__ bsq,
                        const float* __restrict__ gamma, const float* __restrict__ beta,
                        float* __restrict__ sc, float* __restrict__ sh) {
    int c = threadIdx.x;
    if (c >= D) return;
    float mean = bsumv[c] * (1.f / NN);
    float var = bsq[c] * (1.f / NN) - mean * mean;
    float inv = rsqrtf(var + BN_EPS);
    float s = gamma[c] * inv;
    sc[c] = s;
    sh[c] = beta[c] - mean * s;
}

// ------ fused: relu(bn1(u1)) @ g1_W2 + b2 -> relu -> @ g2_W1 = z2 ------------
// tiled: 64 rows/block, LDS k-major stage (BN+ReLU fused), s_load weights,
// cross-wave LDS reduction for the 100->20 stage.
__global__ __launch_bounds__(256) void k_m2(const float* __restrict__ u1,
                                            const float* __restrict__ sc,
                                            const float* __restrict__ sh,
                                            const float* __restrict__ W2,   // [100][100]
                                            const float* __restrict__ b2,
                                            const float* __restrict__ W1p,  // [100][20]
                                            float* __restrict__ z2) {
    __shared__ float Xs[100 * 65];  // 26 KB
    int t = threadIdx.x;
    int row0 = blockIdx.x * 64;
#pragma unroll
    for (int i = 0; i < 25; i++) {
        int p = i * 256 + t;
        int r = p / 100, c = p % 100;
        int row = row0 + r; if (row >= NN) row = NN - 1;
        float v = u1[(size_t)row * D1 + c];
        v = fmaxf(v * sc[c] + sh[c], 0.f);
        Xs[c * 65 + r] = v;
    }
    __syncthreads();
    int cg = __builtin_amdgcn_readfirstlane(t >> 6);
    int r = t & 63;
    int j0 = cg * 25;
    float H[25];
#pragma unroll
    for (int m = 0; m < 25; m++) H[m] = 0.f;
    for (int k = 0; k < D1; k++) {
        float a = Xs[k * 65 + r];
        const float* wr = W2 + k * D1 + j0;  // wave-uniform -> s_load
#pragma unroll
        for (int m = 0; m < 25; m++) H[m] = fmaf(a, wr[m], H[m]);
    }
#pragma unroll
    for (int m = 0; m < 25; m++) H[m] = fmaxf(H[m] + b2[j0 + m], 0.f);
    float pz[20];
#pragma unroll
    for (int c = 0; c < 20; c++) pz[c] = 0.f;
#pragma unroll
    for (int m = 0; m < 25; m++) {
        const float* wp = W1p + (j0 + m) * D2;  // wave-uniform -> s_load
#pragma unroll
        for (int c = 0; c < 20; c++) pz[c] = fmaf(H[m], wp[c], pz[c]);
    }
    __syncthreads();
    float* red = Xs;  // reuse (20 KB needed)
#pragma unroll
    for (int c = 0; c < 20; c++) red[t * 20 + c] = pz[c];
    __syncthreads();
#pragma unroll
    for (int s = 0; s < 5; s++) {
        int p = t * 5 + s;
        int rr = p / 20, c = p % 20;
        float v = red[rr * 20 + c] + red[(64 + rr) * 20 + c] +
                  red[(128 + rr) * 20 + c] + red[(192 + rr) * 20 + c];
        int row = row0 + rr;
        if (row < NN) z2[(size_t)row * D2 + c] = v;
    }
}

// ---------------- u2 = z2 + gather-sum (12 nodes x 20 cols per block) --------
__global__ __launch_bounds__(256) void k_agg2(const float* __restrict__ z2,
                                              const int* __restrict__ offs,
                                              const int* __restrict__ deg,
                                              const int* __restrict__ srcS,
                                              float* __restrict__ u2) {
    int t = threadIdx.x;
    if (t >= 240) return;
    int n = blockIdx.x * 12 + t / 20;
    int c = t % 20;
    if (n >= NN) return;
    int d = deg[n], base = offs[n];
    float a = 0.f, b = 0.f;
    int i = 0;
    for (; i + 2 <= d; i += 2) {
        a += z2[(size_t)srcS[base + i] * D2 + c];
        b += z2[(size_t)srcS[base + i + 1] * D2 + c];
    }
    if (i < d) a += z2[(size_t)srcS[base + i] * D2 + c];
    u2[(size_t)n * D2 + c] = z2[(size_t)n * D2 + c] + a + b;
}

// ------ fused: relu(bn2(u2)) @ g2_W2 + b2 -> relu = h2 ------------
__global__ __launch_bounds__(256) void k_m3(const float* __restrict__ u2,
                                            const float* __restrict__ sc,
                                            const float* __restrict__ sh,
                                            const float* __restrict__ W2pT,
                                            const float* __restrict__ b2p,
                                            float* __restrict__ h2) {
    int row = blockIdx.x * 256 + threadIdx.x;
    if (row >= NN) return;
    float4 y[5];
    const float4* up = (const float4*)(u2 + (size_t)row * D2);
#pragma unroll
    for (int i = 0; i < 5; i++) {
        float4 v = up[i];
        float4 S = *(const float4*)(sc + 4 * i);
        float4 H = *(const float4*)(sh + 4 * i);
        v.x = fmaxf(v.x * S.x + H.x, 0.f);
        v.y = fmaxf(v.y * S.y + H.y, 0.f);
        v.z = fmaxf(v.z * S.z + H.z, 0.f);
        v.w = fmaxf(v.w * S.w + H.w, 0.f);
        y[i] = v;
    }
    float hrow[D2];
#pragma unroll
    for (int j = 0; j < D2; j++) {
        float h = b2p[j];
        const float4* w = (const float4*)(W2pT + j * D2);
#pragma unroll
        for (int kk = 0; kk < 5; kk++) {
            float4 a = y[kk], b = w[kk];
            h += a.x * b.x + a.y * b.y + a.z * b.z + a.w * b.w;
        }
        hrow[j] = fmaxf(h, 0.f);
    }
    float* hr = h2 + (size_t)row * D2;
#pragma unroll
    for (int c = 0; c < D2; c += 4) {
        float4 o; o.x = hrow[c]; o.y = hrow[c + 1]; o.z = hrow[c + 2]; o.w = hrow[c + 3];
        *(float4*)(hr + c) = o;
    }
}

// ---------------- per-graph ranges (node2graph is sorted) ----------------
__global__ void k_starts(const int* __restrict__ n2g, int* __restrict__ starts) {
    int i = blockIdx.x * 256 + threadIdx.x;
    if (i >= NN) return;
    int g = n2g[i];
    if (i == 0) {
        for (int x = 0; x <= g; x++) starts[x] = 0;
    } else {
        int gp = n2g[i - 1];
        for (int x = gp + 1; x <= g; x++) starts[x] = i;
    }
    if (i == NN - 1) {
        for (int x = g + 1; x <= NG; x++) starts[x] = NN;
    }
}

__global__ void k_pool(const float* __restrict__ h2, const int* __restrict__ starts,
                       float* __restrict__ hg) {
    int g = blockIdx.x;
    int j = threadIdx.x;
    if (j >= D2) return;
    int s0 = starts[g], s1 = starts[g + 1];
    float a = 0.f;
    for (int n = s0; n < s1; n++) a += h2[(size_t)n * D2 + j];
    float cnt = (float)(s1 - s0);
    if (cnt < 1.f) cnt = 1.f;
    hg[g * D2 + j] = a / cnt;
}

// ---------------- a1 = kron(hg, self_feat) @ fc1_W ----------------
__global__ void k_head1(const float* __restrict__ hg, const float* __restrict__ sf,
                        const float* __restrict__ fc1W, float* __restrict__ a1) {
    int b = blockIdx.x * 8 + threadIdx.x / 32;
    int c = threadIdx.x % 32;
    if (b >= NG) return;
    const float* hgb = hg + b * D2;
    const float* sfb = sf + b * DSELF;
    float acc = 0.f;
    for (int i = 0; i < D2; i++) {
        float hi = hgb[i];
#pragma unroll
        for (int j = 0; j < DSELF; j++)
            acc += hi * sfb[j] * fc1W[(i * DSELF + j) * 32 + c];
    }
    a1[b * 32 + c] = acc;
}

// ---------------- single-block head: bn1->relu->fc2->bn2->relu->fc3 ----------
__global__ __launch_bounds__(1024) void k_head2(
    const float* __restrict__ a1, const float* __restrict__ g1,
    const float* __restrict__ be1, const float* __restrict__ fc2W,
    const float* __restrict__ g2, const float* __restrict__ be2,
    const float* __restrict__ fc3W, const float* __restrict__ fc3b,
    float* __restrict__ out) {
    int t = threadIdx.x;
    int lane = t & 63, w = t >> 6;
    __shared__ float s1[16][32], s2[16][32];
    __shared__ float sc[32], sh[32], sc2[8], sh2[8];
    float x[32];
    const float4* ap = (const float4*)(a1 + t * 32);
#pragma unroll
    for (int i = 0; i < 8; i++) {
        float4 v = ap[i];
        x[4 * i] = v.x; x[4 * i + 1] = v.y; x[4 * i + 2] = v.z; x[4 * i + 3] = v.w;
    }
#pragma unroll
    for (int c = 0; c < 32; c++) {
        float v = x[c], q = v * v;
        for (int o = 32; o > 0; o >>= 1) {
            v += __shfl_down(v, o, 64);
            q += __shfl_down(q, o, 64);
        }
        if (lane == 0) { s1[w][c] = v; s2[w][c] = q; }
    }
    __syncthreads();
    if (t < 32) {
        float s = 0.f, q = 0.f;
        for (int ww = 0; ww < 16; ww++) { s += s1[ww][t]; q += s2[ww][t]; }
        float mean = s * (1.f / NG);
        float var = q * (1.f / NG) - mean * mean;
        float inv = rsqrtf(var + BN_EPS);
        float scl = g1[t] * inv;
        sc[t] = scl;
        sh[t] = be1[t] - mean * scl;
    }
    __syncthreads();
#pragma unroll
    for (int c = 0; c < 32; c++) x[c] = fmaxf(x[c] * sc[c] + sh[c], 0.f);
    float y[8];
#pragma unroll
    for (int p = 0; p < 8; p++) {
        float a = 0.f;
#pragma unroll
        for (int c = 0; c < 32; c++) a += x[c] * fc2W[c * 8 + p];
        y[p] = a;
    }
    __syncthreads();
#pragma unroll
    for (int p = 0; p < 8; p++) {
        float v = y[p], q = v * v;
        for (int o = 32; o > 0; o >>= 1) {
            v += __shfl_down(v, o, 64);
            q += __shfl_down(q, o, 64);
        }
        if (lane == 0) { s1[w][p] = v; s2[w][p] = q; }
    }
    __syncthreads();
    if (t < 8) {
        float s = 0.f, q = 0.f;
        for (int ww = 0; ww < 16; ww++) { s += s1[ww][t]; q += s2[ww][t]; }
        float mean = s * (1.f / NG);
        float var = q * (1.f / NG) - mean * mean;
        float inv = rsqrtf(var + BN_EPS);
        float scl = g2[t] * inv;
        sc2[t] = scl;
        sh2[t] = be2[t] - mean * scl;
    }
    __syncthreads();
    float o = fc3b[0];
#pragma unroll
    for (int p = 0; p < 8; p++) {
        float yy = fmaxf(y[p] * sc2[p] + sh2[p], 0.f);
        o += yy * fc3W[p];
    }
    out[t] = o;
}

extern "C" void kernel_launch(void* const* d_in, const int* in_sizes, int n_in,
                              void* d_out, int out_size, void* d_ws, size_t ws_size,
                              hipStream_t stream) {
    const float* feat    = (const float*)d_in[0];
    const float* sf      = (const float*)d_in[1];
    const int*   esrc    = (const int*)d_in[2];
    const int*   edst    = (const int*)d_in[3];
    const int*   n2g     = (const int*)d_in[4];
    const float* g1W1    = (const float*)d_in[5];
    const float* g1gam   = (const float*)d_in[7];
    const float* g1bet   = (const float*)d_in[8];
    const float* g1W2    = (const float*)d_in[9];
    const float* g1b2    = (const float*)d_in[10];
    const float* g2W1    = (const float*)d_in[11];
    const float* g2gam   = (const float*)d_in[13];
    const float* g2bet   = (const float*)d_in[14];
    const float* g2W2    = (const float*)d_in[15];
    const float* g2b2    = (const float*)d_in[16];
    const float* fc1W    = (const float*)d_in[17];
    const float* hbn1g   = (const float*)d_in[19];
    const float* hbn1b   = (const float*)d_in[20];
    const float* fc2W    = (const float*)d_in[21];
    const float* hbn2g   = (const float*)d_in[23];
    const float* hbn2b   = (const float*)d_in[24];
    const float* fc3W    = (const float*)d_in[25];
    const float* fc3b    = (const float*)d_in[26];
    float* out = (float*)d_out;

    char* w = (char*)d_ws;
    size_t off = 0;
    auto alloc = [&](size_t bytes) -> char* {
        char* p = w + off;
        off += (bytes + 15) & ~(size_t)15;
        return p;
    };
    float* z1   = (float*)alloc((size_t)NN * D1 * 4);  // reused for z2/u2/h2
    float* u1   = (float*)alloc((size_t)NN * D1 * 4);
    char* zero_base = w + off;
    int*   deg   = (int*)alloc(NN * 4);
    int*   fill  = (int*)alloc(NN * 4);
    float* bn1s  = (float*)alloc(D1 * 4);
    float* bn1q  = (float*)alloc(D1 * 4);
    float* bn2s  = (float*)alloc(D2 * 4);
    float* bn2q  = (float*)alloc(D2 * 4);
    size_t zero_sz = (size_t)((w + off) - zero_base);
    int*   offs  = (int*)alloc(NN * 4);
    int*   bsum  = (int*)alloc(128 * 4);
    int*   srcS  = (int*)alloc((size_t)NE * 4);
    int*   starts= (int*)alloc((NG + 1) * 4);
    float* W2pT  = (float*)alloc(D2 * D2 * 4);
    float* sc1   = (float*)alloc(D1 * 4);
    float* sh1   = (float*)alloc(D1 * 4);
    float* sc2   = (float*)alloc(D2 * 4);
    float* sh2   = (float*)alloc(D2 * 4);
    float* hg    = (float*)alloc(NG * D2 * 4);
    float* a1    = (float*)alloc(NG * 32 * 4);
    float* z2 = z1;
    float* u2 = z1 + 2000000;
    float* h2 = z1 + 4000000;
    (void)in_sizes; (void)n_in; (void)out_size; (void)ws_size;

    hipMemsetAsync(zero_base, 0, zero_sz, stream);

    k_prep<<<2, 256, 0, stream>>>(g2W2, W2pT);
    k_gemm1<<<(NN + 63) / 64, 256, 0, stream>>>(feat, g1W1, z1);

    k_deg<<<(NE + 255) / 256, 256, 0, stream>>>(edst, deg);
    k_scan1<<<98, 1024, 0, stream>>>(deg, offs, bsum);
    k_scan2<<<1, 128, 0, stream>>>(bsum);
    k_scan3<<<(NN + 255) / 256, 256, 0, stream>>>(offs, bsum);
    k_fill<<<(NE + 255) / 256, 256, 0, stream>>>(esrc, edst, offs, fill, srcS);

    k_agg1<<<(NN + 3) / 4, 256, 0, stream>>>(z1, offs, deg, srcS, u1);
    k_bnstat<D1><<<(NN + 255) / 256, 128, 0, stream>>>(u1, bn1s, bn1q);
    k_bnfin<D1><<<1, 128, 0, stream>>>(bn1s, bn1q, g1gam, g1bet, sc1, sh1);
    k_m2<<<(NN + 63) / 64, 256, 0, stream>>>(u1, sc1, sh1, g1W2, g1b2, g2W1, z2);

    k_agg2<<<(NN + 11) / 12, 256, 0, stream>>>(z2, offs, deg, srcS, u2);
    k_bnstat<D2><<<(NN + 255) / 256, 128, 0, stream>>>(u2, bn2s, bn2q);
    k_bnfin<D2><<<1, 128, 0, stream>>>(bn2s, bn2q, g2gam, g2bet, sc2, sh2);
    k_m3<<<(NN + 255) / 256, 256, 0, stream>>>(u2, sc2, sh2, W2pT, g2b2, h2);

    k_starts<<<(NN + 255) / 256, 256, 0, stream>>>(n2g, starts);
    k_pool<<<NG, 64, 0, stream>>>(h2, starts, hg);
    k_head1<<<NG / 8, 256, 0, stream>>>(hg, sf, fc1W, a1);
    k_head2<<<1, 1024, 0, stream>>>(a1, hbn1g, hbn1b, fc2W, hbn2g, hbn2b, fc3W, fc3b, out);
}